// Round 1
// baseline (2883.749 us; speedup 1.0000x reference)
//
#include <hip/hip_runtime.h>
#include <cstdint>
#include <cstddef>

// ---------------------------------------------------------------------------
// LSTM T=512 B=64 I=256 H=512  (fp32 in/out, bf16 MFMA compute)
//
// Phase A (prep):    convert x -> bf16, pack Wall/Uall bf16, ball=bW+bU (f32),
//                    zero the 64 sync flags.
// Phase B (xw_gemm): xw[t*64+b][4H] = x @ Wall^T + ball, stored bf16 (128 MB ws).
// Phase C (scan):    64 persistent WGs = 4 batch-groups x 16 hidden-slices.
//                    U slice lives in VGPRs (128 regs/lane) for all 512 steps.
//                    Per-step sync: per-slice flag (agent-scope atomics),
//                    double-buffered bf16 h exchange. c state in registers.
// ---------------------------------------------------------------------------

typedef __attribute__((ext_vector_type(8))) short short8;
typedef __attribute__((ext_vector_type(4))) float float4v;

__device__ __forceinline__ unsigned short f2bf(float f) {
  unsigned u = __float_as_uint(f);
  u = u + 0x7FFFu + ((u >> 16) & 1u);   // RNE
  return (unsigned short)(u >> 16);
}
__device__ __forceinline__ float bf2f(unsigned short s) {
  return __uint_as_float(((unsigned)s) << 16);
}
__device__ __forceinline__ unsigned long long pack4(float4 v) {
  return (unsigned long long)f2bf(v.x) |
         ((unsigned long long)f2bf(v.y) << 16) |
         ((unsigned long long)f2bf(v.z) << 32) |
         ((unsigned long long)f2bf(v.w) << 48);
}

// ------------------------------ Phase A ------------------------------------
__global__ void prep_kernel(
    const float* __restrict__ x,
    const float* __restrict__ Wf, const float* __restrict__ bWf,
    const float* __restrict__ Wi, const float* __restrict__ bWi,
    const float* __restrict__ Wo, const float* __restrict__ bWo,
    const float* __restrict__ Wc, const float* __restrict__ bWc,
    const float* __restrict__ Uf, const float* __restrict__ bUf,
    const float* __restrict__ Ui, const float* __restrict__ bUi,
    const float* __restrict__ Uo, const float* __restrict__ bUo,
    const float* __restrict__ Uc, const float* __restrict__ bUc,
    unsigned short* __restrict__ xbf, unsigned short* __restrict__ Wall,
    unsigned short* __restrict__ Uall, float* __restrict__ ball,
    int* __restrict__ flags)
{
  const float* Ws[4]  = {Wf, Wi, Wo, Wc};
  const float* Us[4]  = {Uf, Ui, Uo, Uc};
  const float* bWs[4] = {bWf, bWi, bWo, bWc};
  const float* bUs[4] = {bUf, bUi, bUo, bUc};
  const long long NX4 = 2097152;  // 512*64*256/4
  const long long NW4 = 131072;   // 2048*256/4
  const long long NU4 = 262144;   // 2048*512/4
  const long long NB4 = 512;      // 2048/4
  const long long TOT = NX4 + NW4 + NU4 + NB4;
  long long idx0 = (long long)blockIdx.x * blockDim.x + threadIdx.x;
  if (idx0 < 64) flags[idx0] = 0;
  long long stride = (long long)gridDim.x * blockDim.x;
  for (long long u = idx0; u < TOT; u += stride) {
    if (u < NX4) {
      float4 v = ((const float4*)x)[u];
      ((unsigned long long*)xbf)[u] = pack4(v);
    } else if (u < NX4 + NW4) {
      long long q = u - NX4;
      int e = (int)(q << 2);
      int n = e >> 8, k = e & 255;
      float4 v = *(const float4*)(Ws[n >> 9] + (size_t)(n & 511) * 256 + k);
      ((unsigned long long*)Wall)[q] = pack4(v);
    } else if (u < NX4 + NW4 + NU4) {
      long long q = u - NX4 - NW4;
      int e = (int)(q << 2);
      int n = e >> 9, k = e & 511;
      float4 v = *(const float4*)(Us[n >> 9] + (size_t)(n & 511) * 512 + k);
      ((unsigned long long*)Uall)[q] = pack4(v);
    } else {
      long long q = u - NX4 - NW4 - NU4;
      int e = (int)(q << 2);
      int gate = e >> 9, r = e & 511;
      float4 a = *(const float4*)(bWs[gate] + r);
      float4 b = *(const float4*)(bUs[gate] + r);
      float4 sv;
      sv.x = a.x + b.x; sv.y = a.y + b.y; sv.z = a.z + b.z; sv.w = a.w + b.w;
      *(float4*)(ball + e) = sv;
    }
  }
}

// ------------------------------ Phase B ------------------------------------
// xw[m][n] = sum_k xbf[m][k]*Wall[n][k] + ball[n],  M=32768 N=2048 K=256.
// 128x128 tile, BK=64, 4 waves in 2x2, each wave 64x64 (16 accs).
__global__ __launch_bounds__(256, 2) void xw_gemm(
    const unsigned short* __restrict__ xbf,
    const unsigned short* __restrict__ Wall,
    const float* __restrict__ ball,
    unsigned short* __restrict__ xw)
{
  __shared__ short As[128 * 72];
  __shared__ short Bs[128 * 72];
  const int tid = threadIdx.x;
  const int bn = blockIdx.x, bm = blockIdx.y;
  const int Mbase = bm * 128, Nbase = bn * 128;
  const int w = tid >> 6, L = tid & 63, lq = L >> 4, lr = L & 15;
  const int wm = w >> 1, wn = w & 1;
  const int srow = tid >> 1, shalf = tid & 1;  // staging: 64B per thread

  float4v acc[4][4];
  #pragma unroll
  for (int a = 0; a < 4; ++a)
    #pragma unroll
    for (int b = 0; b < 4; ++b) acc[a][b] = (float4v){0.f, 0.f, 0.f, 0.f};

  for (int ko = 0; ko < 256; ko += 64) {
    const unsigned short* ga = xbf + (size_t)(Mbase + srow) * 256 + ko + shalf * 32;
    const unsigned short* gb = Wall + (size_t)(Nbase + srow) * 256 + ko + shalf * 32;
    short8 a0 = *(const short8*)(ga);
    short8 a1 = *(const short8*)(ga + 8);
    short8 a2 = *(const short8*)(ga + 16);
    short8 a3 = *(const short8*)(ga + 24);
    short8 b0 = *(const short8*)(gb);
    short8 b1 = *(const short8*)(gb + 8);
    short8 b2 = *(const short8*)(gb + 16);
    short8 b3 = *(const short8*)(gb + 24);
    __syncthreads();  // protect previous iteration's LDS reads
    {
      short* pa = &As[srow * 72 + shalf * 32];
      short* pb = &Bs[srow * 72 + shalf * 32];
      *(short8*)(pa) = a0; *(short8*)(pa + 8) = a1;
      *(short8*)(pa + 16) = a2; *(short8*)(pa + 24) = a3;
      *(short8*)(pb) = b0; *(short8*)(pb + 8) = b1;
      *(short8*)(pb + 16) = b2; *(short8*)(pb + 24) = b3;
    }
    __syncthreads();
    #pragma unroll
    for (int kk = 0; kk < 64; kk += 32) {
      short8 af[4], bfr[4];
      #pragma unroll
      for (int mi = 0; mi < 4; ++mi)
        af[mi] = *(const short8*)&As[(wm * 64 + mi * 16 + lr) * 72 + kk + lq * 8];
      #pragma unroll
      for (int ni = 0; ni < 4; ++ni)
        bfr[ni] = *(const short8*)&Bs[(wn * 64 + ni * 16 + lr) * 72 + kk + lq * 8];
      #pragma unroll
      for (int mi = 0; mi < 4; ++mi)
        #pragma unroll
        for (int ni = 0; ni < 4; ++ni)
          acc[mi][ni] = __builtin_amdgcn_mfma_f32_16x16x32_bf16(
              af[mi], bfr[ni], acc[mi][ni], 0, 0, 0);
    }
  }
  // epilogue: +bias, bf16 store
  #pragma unroll
  for (int ni = 0; ni < 4; ++ni) {
    int col = Nbase + wn * 64 + ni * 16 + lr;
    float bias = ball[col];
    #pragma unroll
    for (int mi = 0; mi < 4; ++mi) {
      #pragma unroll
      for (int r = 0; r < 4; ++r) {
        int row = Mbase + wm * 64 + mi * 16 + lq * 4 + r;
        xw[(size_t)row * 2048 + col] = f2bf(acc[mi][ni][r] + bias);
      }
    }
  }
}

// ------------------------------ Phase C ------------------------------------
// 64 WGs: g = wg>>4 (batch group, 16 rows), s = wg&15 (hidden slice, 32 cols).
// Wave w (0..3) = gate w (f,i,o,c): U rows w*512+s*32..+32 held in VGPRs.
__global__ __launch_bounds__(256, 1) void lstm_scan(
    const unsigned short* __restrict__ xw,
    const unsigned short* __restrict__ Uall,
    unsigned short* __restrict__ hbuf,   // [2][64][512] bf16
    int* __restrict__ flags,             // [4][16]
    float* __restrict__ out)
{
  __shared__ short hstage[16 * 520];          // h_{t-1} slice, padded rows
  __shared__ float gates[4 * 16 * 33];        // mfma gate outputs (f32)
  __shared__ unsigned short xwb[4 * 16 * 32]; // xw tile (bf16)

  const int tid = threadIdx.x;
  const int wg = blockIdx.x;
  const int g = wg >> 4;
  const int s = wg & 15;
  const int w = tid >> 6, L = tid & 63, lq = L >> 4, lr = L & 15;

  // elementwise ownership: (batch row eb, col pair ej, ej+1)
  const int eb = tid >> 4;
  const int ej = (tid & 15) * 2;
  // xw prefetch mapping: thread -> (batch xb, gate xg, 8-col chunk xc)
  const int xb = tid >> 4, xg = (tid >> 2) & 3, xc = tid & 3;

  float* hseq = out;                                // T*B*H
  float* hfin = out + (size_t)512 * 64 * 512;
  float* cfin = hfin + (size_t)64 * 512;
  int* grp_flags = flags + g * 16;

  // --- U fragments into registers (held across the whole t-loop) ---
  short8 uf[2][16];
  #pragma unroll
  for (int nt = 0; nt < 2; ++nt)
    #pragma unroll
    for (int kt = 0; kt < 16; ++kt) {
      const unsigned short* p = Uall +
          (size_t)(w * 512 + s * 32 + nt * 16 + lr) * 512 + kt * 32 + lq * 8;
      uf[nt][kt] = *(const short8*)p;
    }

  float c0 = 0.f, c1 = 0.f;

  for (int t = 0; t < 512; ++t) {
    // prefetch xw for this step (overlaps the flag spin)
    const unsigned short* xp = xw +
        ((size_t)(t * 64 + g * 16 + xb)) * 2048 + xg * 512 + s * 32 + xc * 8;
    short8 xv = *(const short8*)xp;

    float4v acc0 = (float4v){0.f, 0.f, 0.f, 0.f};
    float4v acc1 = (float4v){0.f, 0.f, 0.f, 0.f};

    if (t > 0) {
      if (tid < 16) {
        while (__hip_atomic_load(&grp_flags[tid], __ATOMIC_RELAXED,
                                 __HIP_MEMORY_SCOPE_AGENT) < t)
          __builtin_amdgcn_s_sleep(1);
      }
      __syncthreads();
      __builtin_amdgcn_fence(__ATOMIC_ACQUIRE, "agent");
      // stage h_{t-1} (16x512 bf16) -> LDS (contiguous per-wave writes)
      const unsigned short* hsrc =
          hbuf + ((size_t)((t - 1) & 1)) * 32768 + (size_t)g * 8192;
      const int scol = (tid & 63) * 8;
      const int sr0 = tid >> 6;
      #pragma unroll
      for (int r = 0; r < 4; ++r) {
        short8 v = *(const short8*)(hsrc + (size_t)(sr0 + r * 4) * 512 + scol);
        *(short8*)&hstage[(sr0 + r * 4) * 520 + scol] = v;
      }
      __syncthreads();
      #pragma unroll
      for (int kt = 0; kt < 16; ++kt) {
        short8 af = *(const short8*)&hstage[lr * 520 + kt * 32 + lq * 8];
        acc0 = __builtin_amdgcn_mfma_f32_16x16x32_bf16(af, uf[0][kt], acc0, 0, 0, 0);
        acc1 = __builtin_amdgcn_mfma_f32_16x16x32_bf16(af, uf[1][kt], acc1, 0, 0, 0);
      }
    }

    // gate tile -> LDS (f32), xw tile -> LDS (bf16)
    #pragma unroll
    for (int r = 0; r < 4; ++r) {
      gates[w * 528 + (lq * 4 + r) * 33 + lr] = acc0[r];
      gates[w * 528 + (lq * 4 + r) * 33 + 16 + lr] = acc1[r];
    }
    *(short8*)&xwb[xg * 512 + xb * 32 + xc * 8] = xv;
    __syncthreads();

    // elementwise LSTM cell for (eb, ej) and (eb, ej+1)
    float h0, h1;
    {
      float gf = gates[eb * 33 + ej] + bf2f(xwb[eb * 32 + ej]);
      float gi = gates[528 + eb * 33 + ej] + bf2f(xwb[512 + eb * 32 + ej]);
      float go = gates[1056 + eb * 33 + ej] + bf2f(xwb[1024 + eb * 32 + ej]);
      float gc = gates[1584 + eb * 33 + ej] + bf2f(xwb[1536 + eb * 32 + ej]);
      float f_ = 1.f / (1.f + __expf(-gf));
      float i_ = 1.f / (1.f + __expf(-gi));
      float o_ = 1.f / (1.f + __expf(-go));
      float ct = 1.f - 2.f / (__expf(2.f * gc) + 1.f);
      c0 = f_ * c0 + i_ * ct;
      h0 = o_ * (1.f - 2.f / (__expf(2.f * c0) + 1.f));
    }
    {
      int j = ej + 1;
      float gf = gates[eb * 33 + j] + bf2f(xwb[eb * 32 + j]);
      float gi = gates[528 + eb * 33 + j] + bf2f(xwb[512 + eb * 32 + j]);
      float go = gates[1056 + eb * 33 + j] + bf2f(xwb[1024 + eb * 32 + j]);
      float gc = gates[1584 + eb * 33 + j] + bf2f(xwb[1536 + eb * 32 + j]);
      float f_ = 1.f / (1.f + __expf(-gf));
      float i_ = 1.f / (1.f + __expf(-gi));
      float o_ = 1.f / (1.f + __expf(-go));
      float ct = 1.f - 2.f / (__expf(2.f * gc) + 1.f);
      c1 = f_ * c1 + i_ * ct;
      h1 = o_ * (1.f - 2.f / (__expf(2.f * c1) + 1.f));
    }
    size_t orow = ((size_t)(t * 64 + g * 16 + eb)) * 512 + s * 32 + ej;
    *(float2*)(hseq + orow) = make_float2(h0, h1);
    unsigned hb = ((unsigned)f2bf(h1) << 16) | (unsigned)f2bf(h0);
    *(unsigned*)(hbuf + ((size_t)(t & 1)) * 32768 +
                 ((size_t)(g * 16 + eb)) * 512 + s * 32 + ej) = hb;
    if (t == 511) {
      size_t fo = ((size_t)(g * 16 + eb)) * 512 + s * 32 + ej;
      *(float2*)(hfin + fo) = make_float2(h0, h1);
      *(float2*)(cfin + fo) = make_float2(c0, c1);
    }
    __syncthreads();  // all global writes drained (vmcnt(0) before barrier)
    if (tid == 0)
      __hip_atomic_store(&grp_flags[s], t + 1, __ATOMIC_RELEASE,
                         __HIP_MEMORY_SCOPE_AGENT);
  }
}

// ------------------------------ launch -------------------------------------
extern "C" void kernel_launch(void* const* d_in, const int* in_sizes, int n_in,
                              void* d_out, int out_size, void* d_ws, size_t ws_size,
                              hipStream_t stream) {
  (void)in_sizes; (void)n_in; (void)out_size; (void)ws_size;
  const float* x   = (const float*)d_in[0];
  const float* Wf  = (const float*)d_in[1];
  const float* bWf = (const float*)d_in[2];
  const float* Wi  = (const float*)d_in[3];
  const float* bWi = (const float*)d_in[4];
  const float* Wo  = (const float*)d_in[5];
  const float* bWo = (const float*)d_in[6];
  const float* Wc  = (const float*)d_in[7];
  const float* bWc = (const float*)d_in[8];
  const float* Uf  = (const float*)d_in[9];
  const float* bUf = (const float*)d_in[10];
  const float* Ui  = (const float*)d_in[11];
  const float* bUi = (const float*)d_in[12];
  const float* Uo  = (const float*)d_in[13];
  const float* bUo = (const float*)d_in[14];
  const float* Uc  = (const float*)d_in[15];
  const float* bUc = (const float*)d_in[16];

  char* ws = (char*)d_ws;
  unsigned short* xw   = (unsigned short*)(ws);                 // 134217728 B
  unsigned short* xbf  = (unsigned short*)(ws + 134217728);     //  16777216 B
  unsigned short* Wall = (unsigned short*)(ws + 150994944);     //   1048576 B
  unsigned short* Uall = (unsigned short*)(ws + 152043520);     //   2097152 B
  float*          ball = (float*)         (ws + 154140672);     //      8192 B
  unsigned short* hbuf = (unsigned short*)(ws + 154148864);     //    131072 B
  int*            flags= (int*)           (ws + 154279936);     //       256 B

  prep_kernel<<<4096, 256, 0, stream>>>(x, Wf, bWf, Wi, bWi, Wo, bWo, Wc, bWc,
                                        Uf, bUf, Ui, bUi, Uo, bUo, Uc, bUc,
                                        xbf, Wall, Uall, ball, flags);
  xw_gemm<<<dim3(16, 256), 256, 0, stream>>>(xbf, Wall, ball, xw);
  lstm_scan<<<64, 256, 0, stream>>>(xw, Uall, hbuf, flags, (float*)d_out);
}

// Round 2
// 1520.899 us; speedup vs baseline: 1.8961x; 1.8961x over previous
//
#include <hip/hip_runtime.h>
#include <cstdint>
#include <cstddef>

// ---------------------------------------------------------------------------
// LSTM T=512 B=64 I=256 H=512  (fp32 in/out, bf16 MFMA compute)
//
// Phase A (prep):    pack Wall/Uall bf16, ball=bW+bU (f32), zero sync flags.
// Phase B (xw_gemm): xw[t*64+b][4H] = x @ Wall^T + ball, bf16 out; x->bf16
//                    conversion fused into A-tile staging.
// Phase C (scan):    64 persistent WGs = 4 batch-groups x 16 hidden-slices.
//                    U slice in VGPRs for all 512 steps. h handoff via
//                    agent-scope RELAXED atomics (cache-bypassing, coherent
//                    at L3) -- NO fences, so L1/L2 stay warm for the xw
//                    stream. Flag publish after __syncthreads() (vmcnt(0)
//                    drain) orders h-stores before the flag.
// ---------------------------------------------------------------------------

typedef __attribute__((ext_vector_type(8))) short short8;
typedef __attribute__((ext_vector_type(4))) float float4v;

__device__ __forceinline__ unsigned short f2bf(float f) {
  unsigned u = __float_as_uint(f);
  u = u + 0x7FFFu + ((u >> 16) & 1u);   // RNE
  return (unsigned short)(u >> 16);
}
__device__ __forceinline__ float bf2f(unsigned short s) {
  return __uint_as_float(((unsigned)s) << 16);
}
__device__ __forceinline__ unsigned long long pack4(float4 v) {
  return (unsigned long long)f2bf(v.x) |
         ((unsigned long long)f2bf(v.y) << 16) |
         ((unsigned long long)f2bf(v.z) << 32) |
         ((unsigned long long)f2bf(v.w) << 48);
}

// ------------------------------ Phase A ------------------------------------
__global__ void prep_kernel(
    const float* __restrict__ Wf, const float* __restrict__ bWf,
    const float* __restrict__ Wi, const float* __restrict__ bWi,
    const float* __restrict__ Wo, const float* __restrict__ bWo,
    const float* __restrict__ Wc, const float* __restrict__ bWc,
    const float* __restrict__ Uf, const float* __restrict__ bUf,
    const float* __restrict__ Ui, const float* __restrict__ bUi,
    const float* __restrict__ Uo, const float* __restrict__ bUo,
    const float* __restrict__ Uc, const float* __restrict__ bUc,
    unsigned short* __restrict__ Wall, unsigned short* __restrict__ Uall,
    float* __restrict__ ball, int* __restrict__ flags)
{
  const float* Ws[4]  = {Wf, Wi, Wo, Wc};
  const float* Us[4]  = {Uf, Ui, Uo, Uc};
  const float* bWs[4] = {bWf, bWi, bWo, bWc};
  const float* bUs[4] = {bUf, bUi, bUo, bUc};
  const long long NW4 = 131072;   // 2048*256/4
  const long long NU4 = 262144;   // 2048*512/4
  const long long NB4 = 512;      // 2048/4
  const long long TOT = NW4 + NU4 + NB4;
  long long idx0 = (long long)blockIdx.x * blockDim.x + threadIdx.x;
  if (idx0 < 64) flags[idx0] = 0;
  long long stride = (long long)gridDim.x * blockDim.x;
  for (long long u = idx0; u < TOT; u += stride) {
    if (u < NW4) {
      int e = (int)(u << 2);
      int n = e >> 8, k = e & 255;
      float4 v = *(const float4*)(Ws[n >> 9] + (size_t)(n & 511) * 256 + k);
      ((unsigned long long*)Wall)[u] = pack4(v);
    } else if (u < NW4 + NU4) {
      long long q = u - NW4;
      int e = (int)(q << 2);
      int n = e >> 9, k = e & 511;
      float4 v = *(const float4*)(Us[n >> 9] + (size_t)(n & 511) * 512 + k);
      ((unsigned long long*)Uall)[q] = pack4(v);
    } else {
      long long q = u - NW4 - NU4;
      int e = (int)(q << 2);
      int gate = e >> 9, r = e & 511;
      float4 a = *(const float4*)(bWs[gate] + r);
      float4 b = *(const float4*)(bUs[gate] + r);
      float4 sv;
      sv.x = a.x + b.x; sv.y = a.y + b.y; sv.z = a.z + b.z; sv.w = a.w + b.w;
      *(float4*)(ball + e) = sv;
    }
  }
}

// ------------------------------ Phase B ------------------------------------
// xw[m][n] = sum_k x[m][k]*Wall[n][k] + ball[n],  M=32768 N=2048 K=256.
// 128x128 tile, BK=64, 4 waves in 2x2, each wave 64x64 (16 accs).
// A staged from f32 x with inline bf16 conversion.
__global__ __launch_bounds__(256, 2) void xw_gemm(
    const float* __restrict__ x,
    const unsigned short* __restrict__ Wall,
    const float* __restrict__ ball,
    unsigned short* __restrict__ xw)
{
  __shared__ short As[128 * 72];
  __shared__ short Bs[128 * 72];
  const int tid = threadIdx.x;
  const int bn = blockIdx.x, bm = blockIdx.y;
  const int Mbase = bm * 128, Nbase = bn * 128;
  const int w = tid >> 6, L = tid & 63, lq = L >> 4, lr = L & 15;
  const int wm = w >> 1, wn = w & 1;
  const int srow = tid >> 1, shalf = tid & 1;  // staging: 32 elems per thread

  float4v acc[4][4];
  #pragma unroll
  for (int a = 0; a < 4; ++a)
    #pragma unroll
    for (int b = 0; b < 4; ++b) acc[a][b] = (float4v){0.f, 0.f, 0.f, 0.f};

  for (int ko = 0; ko < 256; ko += 64) {
    const float* gaf = x + (size_t)(Mbase + srow) * 256 + ko + shalf * 32;
    float4 f0 = *(const float4*)(gaf);
    float4 f1 = *(const float4*)(gaf + 4);
    float4 f2 = *(const float4*)(gaf + 8);
    float4 f3 = *(const float4*)(gaf + 12);
    float4 f4 = *(const float4*)(gaf + 16);
    float4 f5 = *(const float4*)(gaf + 20);
    float4 f6 = *(const float4*)(gaf + 24);
    float4 f7 = *(const float4*)(gaf + 28);
    const unsigned short* gb = Wall + (size_t)(Nbase + srow) * 256 + ko + shalf * 32;
    short8 b0 = *(const short8*)(gb);
    short8 b1 = *(const short8*)(gb + 8);
    short8 b2 = *(const short8*)(gb + 16);
    short8 b3 = *(const short8*)(gb + 24);
    __syncthreads();  // protect previous iteration's LDS reads
    {
      unsigned long long* pa = (unsigned long long*)&As[srow * 72 + shalf * 32];
      pa[0] = pack4(f0); pa[1] = pack4(f1);
      pa[2] = pack4(f2); pa[3] = pack4(f3);
      pa[4] = pack4(f4); pa[5] = pack4(f5);
      pa[6] = pack4(f6); pa[7] = pack4(f7);
      short* pb = &Bs[srow * 72 + shalf * 32];
      *(short8*)(pb) = b0; *(short8*)(pb + 8) = b1;
      *(short8*)(pb + 16) = b2; *(short8*)(pb + 24) = b3;
    }
    __syncthreads();
    #pragma unroll
    for (int kk = 0; kk < 64; kk += 32) {
      short8 af[4], bfr[4];
      #pragma unroll
      for (int mi = 0; mi < 4; ++mi)
        af[mi] = *(const short8*)&As[(wm * 64 + mi * 16 + lr) * 72 + kk + lq * 8];
      #pragma unroll
      for (int ni = 0; ni < 4; ++ni)
        bfr[ni] = *(const short8*)&Bs[(wn * 64 + ni * 16 + lr) * 72 + kk + lq * 8];
      #pragma unroll
      for (int mi = 0; mi < 4; ++mi)
        #pragma unroll
        for (int ni = 0; ni < 4; ++ni)
          acc[mi][ni] = __builtin_amdgcn_mfma_f32_16x16x32_bf16(
              af[mi], bfr[ni], acc[mi][ni], 0, 0, 0);
    }
  }
  // epilogue: +bias, bf16 store
  #pragma unroll
  for (int ni = 0; ni < 4; ++ni) {
    int col = Nbase + wn * 64 + ni * 16 + lr;
    float bias = ball[col];
    #pragma unroll
    for (int mi = 0; mi < 4; ++mi) {
      #pragma unroll
      for (int r = 0; r < 4; ++r) {
        int row = Mbase + wm * 64 + mi * 16 + lq * 4 + r;
        xw[(size_t)row * 2048 + col] = f2bf(acc[mi][ni][r] + bias);
      }
    }
  }
}

// ------------------------------ Phase C ------------------------------------
// 64 WGs: g = wg>>4 (batch group, 16 rows), s = wg&15 (hidden slice, 32 cols).
// Wave w (0..3) = gate w (f,i,o,c): U rows w*512+s*32..+32 held in VGPRs.
// h handoff: relaxed agent atomics (L3-coherent, no fences).
__global__ __launch_bounds__(256, 1) void lstm_scan(
    const unsigned short* __restrict__ xw,
    const unsigned short* __restrict__ Uall,
    unsigned short* __restrict__ hbuf,   // [2][64][512] bf16
    int* __restrict__ flags,             // [4][16]
    float* __restrict__ out)
{
  __shared__ short hstage[16 * 520];          // h_{t-1} slice, padded rows
  __shared__ float gates[4 * 16 * 33];        // mfma gate outputs (f32)
  __shared__ unsigned short xwb[4 * 16 * 32]; // xw tile (bf16)

  const int tid = threadIdx.x;
  const int wg = blockIdx.x;
  const int g = wg >> 4;
  const int s = wg & 15;
  const int w = tid >> 6, L = tid & 63, lq = L >> 4, lr = L & 15;

  // elementwise ownership: (batch row eb, col pair ej, ej+1)
  const int eb = tid >> 4;
  const int ej = (tid & 15) * 2;
  // xw prefetch mapping: thread -> (batch xb, gate xg, 8-col chunk xc)
  const int xb = tid >> 4, xg = (tid >> 2) & 3, xc = tid & 3;

  float* hseq = out;                                // T*B*H
  float* hfin = out + (size_t)512 * 64 * 512;
  float* cfin = hfin + (size_t)64 * 512;
  int* grp_flags = flags + g * 16;

  // --- U fragments into registers (held across the whole t-loop) ---
  short8 uf[2][16];
  #pragma unroll
  for (int nt = 0; nt < 2; ++nt)
    #pragma unroll
    for (int kt = 0; kt < 16; ++kt) {
      const unsigned short* p = Uall +
          (size_t)(w * 512 + s * 32 + nt * 16 + lr) * 512 + kt * 32 + lq * 8;
      uf[nt][kt] = *(const short8*)p;
    }

  float c0 = 0.f, c1 = 0.f, h0 = 0.f, h1 = 0.f;

  for (int t = 0; t < 512; ++t) {
    // prefetch xw for this step (overlaps the flag spin)
    const unsigned short* xp = xw +
        ((size_t)(t * 64 + g * 16 + xb)) * 2048 + xg * 512 + s * 32 + xc * 8;
    short8 xv = *(const short8*)xp;

    float4v a0a = (float4v){0.f, 0.f, 0.f, 0.f};
    float4v a0b = (float4v){0.f, 0.f, 0.f, 0.f};
    float4v a1a = (float4v){0.f, 0.f, 0.f, 0.f};
    float4v a1b = (float4v){0.f, 0.f, 0.f, 0.f};

    if (t > 0) {
      if (tid < 16) {
        while (__hip_atomic_load(&grp_flags[tid], __ATOMIC_RELAXED,
                                 __HIP_MEMORY_SCOPE_AGENT) < t)
          __builtin_amdgcn_s_sleep(1);
      }
      __syncthreads();
      // stage h_{t-1} (16x512 bf16) -> LDS via coherent 8B atomic loads
      const unsigned short* hsrc =
          hbuf + ((size_t)((t - 1) & 1)) * 32768 + (size_t)g * 8192;
      const int scol = (tid & 63) * 8;
      const int sr0 = tid >> 6;
      unsigned long long hv[8];
      #pragma unroll
      for (int r = 0; r < 4; ++r) {
        const unsigned long long* p = (const unsigned long long*)
            (hsrc + (size_t)(sr0 + r * 4) * 512 + scol);
        hv[2 * r]     = __hip_atomic_load(p, __ATOMIC_RELAXED,
                                          __HIP_MEMORY_SCOPE_AGENT);
        hv[2 * r + 1] = __hip_atomic_load(p + 1, __ATOMIC_RELAXED,
                                          __HIP_MEMORY_SCOPE_AGENT);
      }
      #pragma unroll
      for (int r = 0; r < 4; ++r) {
        unsigned long long* q =
            (unsigned long long*)&hstage[(sr0 + r * 4) * 520 + scol];
        q[0] = hv[2 * r]; q[1] = hv[2 * r + 1];
      }
      __syncthreads();
      // 2 parallel dependency chains of 8 MFMAs each per output tile
      #pragma unroll
      for (int kt = 0; kt < 8; ++kt) {
        short8 afA = *(const short8*)&hstage[lr * 520 + kt * 32 + lq * 8];
        short8 afB = *(const short8*)&hstage[lr * 520 + (kt + 8) * 32 + lq * 8];
        a0a = __builtin_amdgcn_mfma_f32_16x16x32_bf16(afA, uf[0][kt], a0a, 0, 0, 0);
        a0b = __builtin_amdgcn_mfma_f32_16x16x32_bf16(afB, uf[0][kt + 8], a0b, 0, 0, 0);
        a1a = __builtin_amdgcn_mfma_f32_16x16x32_bf16(afA, uf[1][kt], a1a, 0, 0, 0);
        a1b = __builtin_amdgcn_mfma_f32_16x16x32_bf16(afB, uf[1][kt + 8], a1b, 0, 0, 0);
      }
    }
    float4v acc0 = a0a + a0b;
    float4v acc1 = a1a + a1b;

    // gate tile -> LDS (f32), xw tile -> LDS (bf16)
    #pragma unroll
    for (int r = 0; r < 4; ++r) {
      gates[w * 528 + (lq * 4 + r) * 33 + lr] = acc0[r];
      gates[w * 528 + (lq * 4 + r) * 33 + 16 + lr] = acc1[r];
    }
    *(short8*)&xwb[xg * 512 + xb * 32 + xc * 8] = xv;
    __syncthreads();

    // elementwise LSTM cell for (eb, ej) and (eb, ej+1)
    {
      float gf = gates[eb * 33 + ej] + bf2f(xwb[eb * 32 + ej]);
      float gi = gates[528 + eb * 33 + ej] + bf2f(xwb[512 + eb * 32 + ej]);
      float go = gates[1056 + eb * 33 + ej] + bf2f(xwb[1024 + eb * 32 + ej]);
      float gc = gates[1584 + eb * 33 + ej] + bf2f(xwb[1536 + eb * 32 + ej]);
      float f_ = 1.f / (1.f + __expf(-gf));
      float i_ = 1.f / (1.f + __expf(-gi));
      float o_ = 1.f / (1.f + __expf(-go));
      float ct = 1.f - 2.f / (__expf(2.f * gc) + 1.f);
      c0 = f_ * c0 + i_ * ct;
      h0 = o_ * (1.f - 2.f / (__expf(2.f * c0) + 1.f));
    }
    {
      int j = ej + 1;
      float gf = gates[eb * 33 + j] + bf2f(xwb[eb * 32 + j]);
      float gi = gates[528 + eb * 33 + j] + bf2f(xwb[512 + eb * 32 + j]);
      float go = gates[1056 + eb * 33 + j] + bf2f(xwb[1024 + eb * 32 + j]);
      float gc = gates[1584 + eb * 33 + j] + bf2f(xwb[1536 + eb * 32 + j]);
      float f_ = 1.f / (1.f + __expf(-gf));
      float i_ = 1.f / (1.f + __expf(-gi));
      float o_ = 1.f / (1.f + __expf(-go));
      float ct = 1.f - 2.f / (__expf(2.f * gc) + 1.f);
      c1 = f_ * c1 + i_ * ct;
      h1 = o_ * (1.f - 2.f / (__expf(2.f * c1) + 1.f));
    }
    // hseq out (nontemporal 8B; never read back in-kernel)
    size_t orow = ((size_t)(t * 64 + g * 16 + eb)) * 512 + s * 32 + ej;
    {
      float2 hv2 = make_float2(h0, h1);
      __builtin_nontemporal_store(*(double*)&hv2, (double*)(hseq + orow));
    }
    // h handoff (coherent 4B atomic store to L3)
    unsigned hb = ((unsigned)f2bf(h1) << 16) | (unsigned)f2bf(h0);
    unsigned* hdst = (unsigned*)(hbuf + ((size_t)(t & 1)) * 32768 +
                                 ((size_t)(g * 16 + eb)) * 512 + s * 32 + ej);
    __hip_atomic_store(hdst, hb, __ATOMIC_RELAXED, __HIP_MEMORY_SCOPE_AGENT);

    __syncthreads();  // vmcnt(0) drain: all h stores at L3 before flag
    if (tid == 0)
      __hip_atomic_store(&grp_flags[s], t + 1, __ATOMIC_RELAXED,
                         __HIP_MEMORY_SCOPE_AGENT);
  }

  // final states
  size_t fo = ((size_t)(g * 16 + eb)) * 512 + s * 32 + ej;
  *(float2*)(hfin + fo) = make_float2(h0, h1);
  *(float2*)(cfin + fo) = make_float2(c0, c1);
}

// ------------------------------ launch -------------------------------------
extern "C" void kernel_launch(void* const* d_in, const int* in_sizes, int n_in,
                              void* d_out, int out_size, void* d_ws, size_t ws_size,
                              hipStream_t stream) {
  (void)in_sizes; (void)n_in; (void)out_size; (void)ws_size;
  const float* x   = (const float*)d_in[0];
  const float* Wf  = (const float*)d_in[1];
  const float* bWf = (const float*)d_in[2];
  const float* Wi  = (const float*)d_in[3];
  const float* bWi = (const float*)d_in[4];
  const float* Wo  = (const float*)d_in[5];
  const float* bWo = (const float*)d_in[6];
  const float* Wc  = (const float*)d_in[7];
  const float* bWc = (const float*)d_in[8];
  const float* Uf  = (const float*)d_in[9];
  const float* bUf = (const float*)d_in[10];
  const float* Ui  = (const float*)d_in[11];
  const float* bUi = (const float*)d_in[12];
  const float* Uo  = (const float*)d_in[13];
  const float* bUo = (const float*)d_in[14];
  const float* Uc  = (const float*)d_in[15];
  const float* bUc = (const float*)d_in[16];

  char* ws = (char*)d_ws;
  unsigned short* xw   = (unsigned short*)(ws);                 // 134217728 B
  unsigned short* Wall = (unsigned short*)(ws + 134217728);     //   1048576 B
  unsigned short* Uall = (unsigned short*)(ws + 135266304);     //   2097152 B
  float*          ball = (float*)         (ws + 137363456);     //      8192 B
  unsigned short* hbuf = (unsigned short*)(ws + 137371648);     //    131072 B
  int*            flags= (int*)           (ws + 137502720);     //       256 B

  prep_kernel<<<768, 256, 0, stream>>>(Wf, bWf, Wi, bWi, Wo, bWo, Wc, bWc,
                                       Uf, bUf, Ui, bUi, Uo, bUo, Uc, bUc,
                                       Wall, Uall, ball, flags);
  xw_gemm<<<dim3(16, 256), 256, 0, stream>>>(x, Wall, ball, xw);
  lstm_scan<<<64, 256, 0, stream>>>(xw, Uall, hbuf, flags, (float*)d_out);
}